// Round 2
// baseline (491.620 us; speedup 1.0000x reference)
//
#include <hip/hip_runtime.h>

// TopKActivation: per row of [4096, 16384] fp32, keep top-k (k=128) values in
// place, zero the rest. One block per row; row lives in registers (64 elems /
// thread); exact threshold via bitwise binary search with ballot-counting,
// then a compacted-LDS refinement; single read pass + single write pass.

constexpr int COLS  = 16384;
constexpr int NT    = 256;             // threads per block
constexpr int PER_T = COLS / NT;       // 64 elements per thread
constexpr int NV4   = PER_T / 4;       // 16 float4 per thread
constexpr int CAP   = 2048;            // compacted-candidate capacity

// Monotone float->uint key: order(key) == order(float), all finite values.
__device__ __forceinline__ unsigned int f2key(float f) {
  unsigned int b = __float_as_uint(f);
  return b ^ ((unsigned int)((int)b >> 31) | 0x80000000u);
}
__device__ __forceinline__ float key2f(unsigned int k) {
  unsigned int b = (k & 0x80000000u) ? (k ^ 0x80000000u) : ~k;
  return __uint_as_float(b);
}

__global__ void __launch_bounds__(NT)
topk_scatter_kernel(const float* __restrict__ x, const int* __restrict__ kptr,
                    float* __restrict__ out) {
  const int t    = threadIdx.x;
  const int lane = t & 63;
  const int wid  = t >> 6;
  const long long row = blockIdx.x;
  const int K = *kptr;   // 128

  __shared__ int red[2][4];                 // per-wave counts, parity-buffered
  __shared__ unsigned int cand[CAP];        // compacted candidate keys
  __shared__ int cand_n;
  __shared__ unsigned int flags[COLS / 32]; // rare-path tie bitmask (2 KB)

  const float4* xrow = reinterpret_cast<const float4*>(x + row * COLS);
  float4*       orow = reinterpret_cast<float4*>(out + row * COLS);

  // ---- load + transform; keys stay in registers -------------------------
  unsigned int key[PER_T];
  #pragma unroll
  for (int r = 0; r < NV4; ++r) {
    float4 v = xrow[r * NT + t];
    key[4 * r + 0] = f2key(v.x);
    key[4 * r + 1] = f2key(v.y);
    key[4 * r + 2] = f2key(v.z);
    key[4 * r + 3] = f2key(v.w);
  }

  // ---- exact k-th largest key via binary search on key bits -------------
  // Invariants: count_ge(lo) >= K (cnt_lo), count_ge(hi+1) < K (cnt_hi1).
  unsigned int lo = 0u, hi = 0xFFFFFFFFu;
  int cnt_lo = COLS, cnt_hi1 = 0;
  int base = 0, cN = 0;
  bool compacted = false;
  int par = 0;

  while (lo < hi) {
    const unsigned int mid = lo + ((hi - lo) >> 1) + 1u;  // in [lo+1, hi]
    int c;
    if (!compacted) {
      // full-data count: 1 v_cmp + popc per 64 elements, wave-uniform result
      int cw = 0;
      #pragma unroll
      for (int r = 0; r < PER_T; ++r)
        cw += __popcll(__ballot(key[r] >= mid));
      if (lane == 0) red[par][wid] = cw;
      __syncthreads();
      c = red[par][0] + red[par][1] + red[par][2] + red[par][3];
      par ^= 1;
    } else {
      // each wave redundantly counts the whole compacted list: no barriers
      int cw = 0;
      for (int j0 = 0; j0 < cN; j0 += 64) {
        const int j = j0 + lane;
        const unsigned int v = (j < cN) ? cand[j] : 0u;  // mid >= 1, so 0 fails
        cw += __popcll(__ballot(v >= mid));
      }
      c = base + cw;
    }

    if (c >= K) { lo = mid; cnt_lo = c; }
    else        { hi = mid - 1u; cnt_hi1 = c; }

    if (!compacted && lo < hi && (cnt_lo - cnt_hi1) <= CAP) {
      // compact all keys in [lo, hi] into LDS; exactly cnt_lo - cnt_hi1 of them
      if (t == 0) cand_n = 0;
      __syncthreads();
      #pragma unroll
      for (int r = 0; r < PER_T; ++r) {
        const unsigned int kk = key[r];
        if (kk >= lo && kk <= hi) {
          const int p = atomicAdd(&cand_n, 1);
          cand[p] = kk;
        }
      }
      __syncthreads();
      cN = cnt_lo - cnt_hi1;
      base = cnt_hi1;
      compacted = true;
    }
  }

  const unsigned int T = lo;           // k-th largest key
  const int E = cnt_lo - cnt_hi1;      // # elements equal to T
  const int R = K - cnt_hi1;           // how many equals to keep (>=1)
  const bool need_rank = (E != R);     // duplicates straddling the boundary

  if (need_rank) {
    // rare path: mark all equal elements, keep the R lowest-indexed ones
    for (int w = t; w < COLS / 32; w += NT) flags[w] = 0u;
    __syncthreads();
    #pragma unroll
    for (int r = 0; r < NV4; ++r) {
      #pragma unroll
      for (int j = 0; j < 4; ++j) {
        if (key[4 * r + j] == T) {
          const int col = (r * NT + t) * 4 + j;
          atomicOr(&flags[col >> 5], 1u << (col & 31));
        }
      }
    }
    __syncthreads();
  }

  // ---- write pass: val if kept, else 0 ----------------------------------
  #pragma unroll
  for (int r = 0; r < NV4; ++r) {
    float vals[4];
    #pragma unroll
    for (int j = 0; j < 4; ++j) {
      const unsigned int kk = key[4 * r + j];
      bool keep;
      if (kk > T) {
        keep = true;
      } else if (kk == T) {
        if (!need_rank) {
          keep = true;
        } else {
          const int col = (r * NT + t) * 4 + j;
          const int w_hi = col >> 5;
          int rank = 0;
          for (int w = 0; w < w_hi; ++w) rank += __popc(flags[w]);
          rank += __popc(flags[w_hi] & ((1u << (col & 31)) - 1u));
          keep = (rank < R);
        }
      } else {
        keep = false;
      }
      vals[j] = keep ? key2f(kk) : 0.0f;
    }
    orow[r * NT + t] = make_float4(vals[0], vals[1], vals[2], vals[3]);
  }
}

extern "C" void kernel_launch(void* const* d_in, const int* in_sizes, int n_in,
                              void* d_out, int out_size, void* d_ws, size_t ws_size,
                              hipStream_t stream) {
  const float* x    = (const float*)d_in[0];
  const int*   kptr = (const int*)d_in[1];
  float*       out  = (float*)d_out;
  const int rows = in_sizes[0] / COLS;  // 4096
  topk_scatter_kernel<<<rows, NT, 0, stream>>>(x, kptr, out);
}